// Round 6
// baseline (208.733 us; speedup 1.0000x reference)
//
#include <hip/hip_runtime.h>

// YOLO v1 loss, two-kernel fused reduction.
// input_: [B, 30, 7, 7] fp32   (channel-major per image, 1470 floats/batch)
// target: [B, 7, 7, 30] fp32   (cell-major, 30 contiguous per cell)
// out   : [1] fp32 scalar loss
//
// Round-6: Rounds 3-5 showed every compiler-scheduled variant pins at
// ~1.4 TB/s HBM because loads are sunk to their uses (VGPR=36) or drained
// behind a monolithic barrier. Fix: issue ALL 45 loads per thread as
// asm-volatile global_load (un-sinkable, un-splittable), one s_waitcnt
// vmcnt(0), sched_barrier(0) (rule #18), then compute. ~180 B in flight per
// thread => ~45 KB/CU outstanding vs ~9 KB needed for 6.3 TB/s.

typedef float f32x2 __attribute__((ext_vector_type(2)));

#define CELLF   64.0f
#define IMGF    448.0f
#define EPSF    1e-6f
#define LAMBDA_COORD 5.0f
#define LAMBDA_NOOBJ 0.5f

#define TPB 256

__global__ __launch_bounds__(TPB) void yolo_main(
    const float* __restrict__ input,
    const float* __restrict__ target,
    float* __restrict__ partial,
    int ncells)
{
    const int tid = threadIdx.x;
    const int n   = blockIdx.x * TPB + tid;

    float lv = 0.0f;
    if (n < ncells) {
        const int b    = n / 49;
        const int cell = n - b * 49;
        const int row  = cell / 7;
        const int col  = cell - row * 7;

        // input channel c lives at byte offset c*196 from this cell's base;
        // shift base by +2744 so offsets span [-2744, 2940] (13-bit signed imm)
        const char* xa = (const char*)(input + (size_t)b * 1470 + cell) + 2744;
        const char* ta = (const char*)(target + (size_t)n * 30);   // 8B-aligned

        float x[30];
        f32x2 tv[15];

#define LDX(i, OFF) asm volatile("global_load_dword %0, %1, off offset:" OFF \
                                 : "=v"(x[i]) : "v"(xa))
#define LDT(i, OFF) asm volatile("global_load_dwordx2 %0, %1, off offset:" OFF \
                                 : "=v"(tv[i]) : "v"(ta))
        LDX(0, "-2744"); LDX(1, "-2548"); LDX(2, "-2352"); LDX(3, "-2156");
        LDX(4, "-1960"); LDX(5, "-1764"); LDX(6, "-1568"); LDX(7, "-1372");
        LDX(8, "-1176"); LDX(9, "-980");  LDX(10, "-784"); LDX(11, "-588");
        LDX(12, "-392"); LDX(13, "-196"); LDX(14, "0");    LDX(15, "196");
        LDX(16, "392");  LDX(17, "588");  LDX(18, "784");  LDX(19, "980");
        LDX(20, "1176"); LDX(21, "1372"); LDX(22, "1568"); LDX(23, "1764");
        LDX(24, "1960"); LDX(25, "2156"); LDX(26, "2352"); LDX(27, "2548");
        LDX(28, "2744"); LDX(29, "2940");

        LDT(0, "0");   LDT(1, "8");   LDT(2, "16");  LDT(3, "24");
        LDT(4, "32");  LDT(5, "40");  LDT(6, "48");  LDT(7, "56");
        LDT(8, "64");  LDT(9, "72");  LDT(10, "80"); LDT(11, "88");
        LDT(12, "96"); LDT(13, "104"); LDT(14, "112");
#undef LDX
#undef LDT

        asm volatile("s_waitcnt vmcnt(0)" ::: "memory");
        __builtin_amdgcn_sched_barrier(0);   // rule #18: keep uses after the wait

        float t[30];
        #pragma unroll
        for (int j = 0; j < 15; ++j) {
            t[2 * j]     = tv[j].x;
            t[2 * j + 1] = tv[j].y;
        }

        const float colf = (float)col * CELLF;
        const float rowf = (float)row * CELLF;

        float iou[2];
        #pragma unroll
        for (int k = 0; k < 2; ++k) {
            const int o = 5 * k;
            float pcx = x[o + 0] * CELLF + colf;
            float pcy = x[o + 1] * CELLF + rowf;
            float pw  = x[o + 2] * IMGF;
            float ph  = x[o + 3] * IMGF;
            float px1 = fminf(fmaxf(pcx - 0.5f * pw, 0.0f), IMGF);
            float py1 = fminf(fmaxf(pcy - 0.5f * ph, 0.0f), IMGF);
            float px2 = fminf(fmaxf(pcx + 0.5f * pw, 0.0f), IMGF);
            float py2 = fminf(fmaxf(pcy + 0.5f * ph, 0.0f), IMGF);

            float tcx = t[o + 0] * CELLF + colf;
            float tcy = t[o + 1] * CELLF + rowf;
            float tw  = t[o + 2] * IMGF;
            float th  = t[o + 3] * IMGF;
            float tx1 = fminf(fmaxf(tcx - 0.5f * tw, 0.0f), IMGF);
            float ty1 = fminf(fmaxf(tcy - 0.5f * th, 0.0f), IMGF);
            float tx2 = fminf(fmaxf(tcx + 0.5f * tw, 0.0f), IMGF);
            float ty2 = fminf(fmaxf(tcy + 0.5f * th, 0.0f), IMGF);

            float iw = fmaxf(fminf(px2, tx2) - fmaxf(px1, tx1), EPSF);
            float ih = fmaxf(fminf(py2, ty2) - fmaxf(py1, ty1), EPSF);
            float inter = iw * ih;
            float area  = (px2 - px1) * (py2 - py1) + (tx2 - tx1) * (ty2 - ty1);
            iou[k] = inter / (area - inter);
        }

        const bool  m      = iou[0] < iou[1];
        const float iouSel = m ? iou[1] : iou[0];
        const float has_obj = (t[4] == 1.0f) ? 1.0f : 0.0f;
        const float no_obj  = 1.0f - has_obj;

        const float s0 = m ? x[5] : x[0];
        const float s1 = m ? x[6] : x[1];
        const float s2 = m ? x[7] : x[2];
        const float s3 = m ? x[8] : x[3];
        const float s4 = m ? x[9] : x[4];

        float d0 = s0 - t[0], d1 = s1 - t[1];
        float coord_e = d0 * d0 + d1 * d1;

        float e2 = sqrtf(s2) - sqrtf(t[2]);
        float e3 = sqrtf(s3) - sqrtf(t[3]);
        float size_e = e2 * e2 + e3 * e3;

        float dc = s4 - iouSel;
        float conf_e = dc * dc;

        float cls_e = 0.0f;
        #pragma unroll
        for (int c = 10; c < 30; ++c) {
            float d = x[c] - t[c];
            cls_e += d * d;
        }

        float noobj_e = x[4] * x[4] + x[9] * x[9];

        lv = has_obj * (LAMBDA_COORD * coord_e + LAMBDA_COORD * size_e + conf_e + cls_e)
           + LAMBDA_NOOBJ * no_obj * noobj_e;
    }

    // ---- reduce: wave shuffle, then cross-wave via LDS ----
    #pragma unroll
    for (int off = 32; off > 0; off >>= 1)
        lv += __shfl_down(lv, off, 64);

    __shared__ float s_part[TPB / 64];
    if ((tid & 63) == 0) s_part[tid >> 6] = lv;
    __syncthreads();

    if (tid == 0) {
        float tot = 0.0f;
        #pragma unroll
        for (int w = 0; w < TPB / 64; ++w) tot += s_part[w];
        partial[blockIdx.x] = tot;
    }
}

__global__ __launch_bounds__(256) void yolo_reduce(
    const float* __restrict__ partial, int nparts,
    float* __restrict__ out, float inv_b)
{
    const int tid = threadIdx.x;
    float v = 0.0f;
    for (int i = tid; i < nparts; i += 256) v += partial[i];

    #pragma unroll
    for (int off = 32; off > 0; off >>= 1)
        v += __shfl_down(v, off, 64);

    __shared__ float s_part[4];
    if ((tid & 63) == 0) s_part[tid >> 6] = v;
    __syncthreads();

    if (tid == 0)
        out[0] = (s_part[0] + s_part[1] + s_part[2] + s_part[3]) * inv_b;
}

extern "C" void kernel_launch(void* const* d_in, const int* in_sizes, int n_in,
                              void* d_out, int out_size, void* d_ws, size_t ws_size,
                              hipStream_t stream) {
    const float* input  = (const float*)d_in[0];
    const float* target = (const float*)d_in[1];
    float* out = (float*)d_out;
    float* partial = (float*)d_ws;

    const int B = in_sizes[0] / (30 * 49);         // 16384
    const int ncells = B * 49;                     // 802816
    const int nblocks = (ncells + TPB - 1) / TPB;  // 3136

    yolo_main<<<nblocks, TPB, 0, stream>>>(input, target, partial, ncells);
    yolo_reduce<<<1, 256, 0, stream>>>(partial, nblocks, out, 1.0f / (float)B);
}